// Round 11
// baseline (755.154 us; speedup 1.0000x reference)
//
#include <hip/hip_runtime.h>

#define N_RID  100000
#define N_CELL 400000
#define NCOLS  4
#define NE     100000
#define D      64
#define TOTE   (NCOLS * NE)          // 400000 edges per direction
#define TILE   64                    // rows per block
#define NBF    (NCOLS * N_CELL)
#define NBR    (NCOLS * N_RID)
#define NCHF   ((NBF + 1023) / 1024) // 1563
#define NCHR   ((NBR + 1023) / 1024) // 391

typedef __attribute__((ext_vector_type(8))) short bf16x8;
typedef __attribute__((ext_vector_type(4))) float f32x4;

__device__ inline unsigned short f2bf(float f) {
    unsigned int u = __float_as_uint(f);
    return (unsigned short)((u + 0x7FFF + ((u >> 16) & 1)) >> 16);
}
__device__ inline float bf2f(unsigned short b) {
    return __uint_as_float(((unsigned int)b) << 16);
}
__device__ inline unsigned int cvtpk(float a, float b) {
    unsigned int r;
    asm("v_cvt_pk_bf16_f32 %0, %1, %2" : "=v"(r) : "v"(a), "v"(b));
    return r;
}
// byte offset within a [16 rows][128B] bf16 tile, XOR-swizzled
__device__ inline int swz(int row, int kbyte) {
    return row * 128 + (kbyte ^ ((row & 7) << 4));
}
template<bool BF>
__device__ inline void ldrow(const void* h, size_t row, int q, float4& a, float4& b) {
    if (BF) {
        const unsigned short* p = (const unsigned short*)h + row * D + q * 8;
        bf16x8 r = *(const bf16x8*)p;
        a.x = bf2f((unsigned short)r[0]); a.y = bf2f((unsigned short)r[1]);
        a.z = bf2f((unsigned short)r[2]); a.w = bf2f((unsigned short)r[3]);
        b.x = bf2f((unsigned short)r[4]); b.y = bf2f((unsigned short)r[5]);
        b.z = bf2f((unsigned short)r[6]); b.w = bf2f((unsigned short)r[7]);
    } else {
        const float4* p = (const float4*)((const float*)h + row * D);
        a = p[2 * q]; b = p[2 * q + 1];
    }
}

// ================================================================ CSR build (merged F+R)
__global__ void hist2(const int* __restrict__ dstF, const int* __restrict__ dstR,
                      int* __restrict__ cntF, int* __restrict__ cntR) {
    int t = blockIdx.x * 256 + threadIdx.x;
    if (t < TOTE) {
        int c = t / NE;
        atomicAdd(&cntF[c * N_CELL + dstF[t]], 1);
    } else if (t < 2 * TOTE) {
        int t2 = t - TOTE;
        int c = t2 / NE;
        atomicAdd(&cntR[c * N_RID + dstR[t2]], 1);
    }
}

__global__ void scan1_2(const int* __restrict__ inF, int* __restrict__ outF,
                        int* __restrict__ csF, const int* __restrict__ inR,
                        int* __restrict__ outR, int* __restrict__ csR) {
    __shared__ int lds[256];
    const int b = blockIdx.x;
    const int* in; int* outp; int* cs; int n, bb;
    if (b < NCHF) { in = inF; outp = outF; cs = csF; n = NBF; bb = b; }
    else          { in = inR; outp = outR; cs = csR; n = NBR; bb = b - NCHF; }
    int base = bb * 1024 + threadIdx.x * 4;
    int v0 = 0, v1 = 0, v2 = 0, v3 = 0;
    if (base + 0 < n) v0 = in[base + 0];
    if (base + 1 < n) v1 = in[base + 1];
    if (base + 2 < n) v2 = in[base + 2];
    if (base + 3 < n) v3 = in[base + 3];
    int tsum = v0 + v1 + v2 + v3;
    lds[threadIdx.x] = tsum;
    __syncthreads();
    for (int off = 1; off < 256; off <<= 1) {
        int x = (threadIdx.x >= off) ? lds[threadIdx.x - off] : 0;
        __syncthreads();
        lds[threadIdx.x] += x;
        __syncthreads();
    }
    int excl = lds[threadIdx.x] - tsum;
    if (base + 0 < n) outp[base + 0] = excl;
    if (base + 1 < n) outp[base + 1] = excl + v0;
    if (base + 2 < n) outp[base + 2] = excl + v0 + v1;
    if (base + 3 < n) outp[base + 3] = excl + v0 + v1 + v2;
    if (threadIdx.x == 255) cs[bb] = lds[255];
}

__global__ void scan2_2(int* __restrict__ aF, int* __restrict__ aR) {
    __shared__ int lds[256];
    int* a = blockIdx.x ? aR : aF;
    int m  = blockIdx.x ? NCHR : NCHF;
    int per = (m + 255) >> 8;
    int st = threadIdx.x * per;
    int s = 0;
    for (int i = 0; i < per; ++i) if (st + i < m) s += a[st + i];
    lds[threadIdx.x] = s;
    __syncthreads();
    for (int off = 1; off < 256; off <<= 1) {
        int x = (threadIdx.x >= off) ? lds[threadIdx.x - off] : 0;
        __syncthreads();
        lds[threadIdx.x] += x;
        __syncthreads();
    }
    int run = lds[threadIdx.x] - s;
    for (int i = 0; i < per; ++i) if (st + i < m) { int v = a[st + i]; a[st + i] = run; run += v; }
}

__global__ void scan3_2(int* __restrict__ outF, const int* __restrict__ csF,
                        int* __restrict__ outR, const int* __restrict__ csR) {
    const int gF = (NBF + 255) / 256;
    int b = blockIdx.x;
    if (b == 0 && threadIdx.x == 0) { outF[NBF] = TOTE; outR[NBR] = TOTE; }
    if (b < gF) {
        int i = b * 256 + threadIdx.x;
        if (i < NBF) outF[i] += csF[i >> 10];
    } else {
        int i = (b - gF) * 256 + threadIdx.x;
        if (i < NBR) outR[i] += csR[i >> 10];
    }
}

__global__ void fill2(const int* __restrict__ dstF, const int* __restrict__ srcF,
                      const int* __restrict__ ptrF, int* __restrict__ cntF,
                      int* __restrict__ colF,
                      const int* __restrict__ dstR, const int* __restrict__ srcR,
                      const int* __restrict__ ptrR, int* __restrict__ cntR,
                      int* __restrict__ colR) {
    int t = blockIdx.x * 256 + threadIdx.x;
    if (t < TOTE) {
        int c = t / NE;
        int bin = c * N_CELL + dstF[t];
        int old = atomicSub(&cntF[bin], 1);
        colF[ptrF[bin] + old - 1] = srcF[t];
    } else if (t < 2 * TOTE) {
        int t2 = t - TOTE;
        int c = t2 / NE;
        int bin = c * N_RID + dstR[t2];
        int old = atomicSub(&cntR[bin], 1);
        colR[ptrR[bin] + old - 1] = srcR[t2];
    }
}

// ---------------- W prep: Wt[c][j][k] = bf16(W[c][k][j])
__global__ void prep_w(const float* __restrict__ Wa, const float* __restrict__ Wb,
                       const float* __restrict__ Wc, const float* __restrict__ Wd,
                       unsigned short* __restrict__ Ta, unsigned short* __restrict__ Tb,
                       unsigned short* __restrict__ Tc, unsigned short* __restrict__ Td) {
    int t = blockIdx.x * 256 + threadIdx.x;
    if (t >= NCOLS * D * D) return;
    int c = t >> 12, jk = t & 4095, j = jk >> 6, k = jk & 63;
    int s = (c * D + k) * D + j;
    Ta[t] = f2bf(Wa[s]);
    Tb[t] = f2bf(Wb[s]);
    Tc[t] = f2bf(Wc[s]);
    Td[t] = f2bf(Wd[s]);
}

// ============================ unified SAGE layer kernel ======================
// V=0 full; V=1 skip gather; V=2 skip transform (no W/cvt/LDS-A/MFMA).
// Epilogue stages through per-wave LDS and writes FULL cache lines.
template<int V, bool INBF, bool OUTBF>
__global__ void __launch_bounds__(256, 4) sage2(
        const void* __restrict__ hdC, const void* __restrict__ hsC,
        const int* __restrict__ ptrC, const int* __restrict__ colC,
        const unsigned short* __restrict__ WtC, const float* __restrict__ biasC,
        const float* __restrict__ mudC, const float* __restrict__ musC,
        void* __restrict__ outC, float* __restrict__ csC,
        const void* __restrict__ hdR, const void* __restrict__ hsR,
        const int* __restrict__ ptrR, const int* __restrict__ colR,
        const unsigned short* __restrict__ WtR, const float* __restrict__ biasR,
        const float* __restrict__ mudR, const float* __restrict__ musR,
        void* __restrict__ outR, float* __restrict__ csR, int gC) {
    __shared__ int pl[NCOLS][TILE + 1];
    __shared__ __align__(16) unsigned short aBuf[4][2][16 * D];  // [wave][hi/lo][tile]

    const int tid = threadIdx.x, w = tid >> 6, l = tid & 63;
    const int g = l >> 3, q = l & 7;

    const bool rrole = (int)blockIdx.x >= gC;
    const void* h_dst = rrole ? hdR : hdC;
    const void* h_src = rrole ? hsR : hsC;
    const int* ptr    = rrole ? ptrR : ptrC;
    const int* col    = rrole ? colR : colC;
    const unsigned short* Wt = rrole ? WtR : WtC;
    const float* bias = rrole ? biasR : biasC;
    const float* mu_d = rrole ? mudR : mudC;
    const float* mu_s = rrole ? musR : musC;
    void* out   = rrole ? outR : outC;
    float* csum = rrole ? csR : csC;
    const int n_dst = rrole ? N_RID : N_CELL;
    const int row0 = (rrole ? (int)blockIdx.x - gC : (int)blockIdx.x) * TILE;

    for (int i = tid; i < NCOLS * (TILE + 1); i += 256) {
        int cc = i / (TILE + 1), r = i % (TILE + 1);
        pl[cc][r] = ptr[(size_t)cc * n_dst + min(row0 + r, n_dst)];
    }

    // self term, fanned to 4 relations
    float4 t0[NCOLS][2], t1[NCOLS][2];
#pragma unroll
    for (int i = 0; i < 2; ++i) {
        int re = min(row0 + w * 16 + i * 8 + g, n_dst - 1);
        float4 v0, v1;
        ldrow<INBF>(h_dst, (size_t)re, q, v0, v1);
        if (mu_d) {
            float4 m0 = ((const float4*)mu_d)[2 * q], m1 = ((const float4*)mu_d)[2 * q + 1];
            v0.x -= m0.x; v0.y -= m0.y; v0.z -= m0.z; v0.w -= m0.w;
            v1.x -= m1.x; v1.y -= m1.y; v1.z -= m1.z; v1.w -= m1.w;
        }
#pragma unroll
        for (int c = 0; c < NCOLS; ++c) { t0[c][i] = v0; t1[c][i] = v1; }
    }
    float4 ms0 = {0, 0, 0, 0}, ms1 = {0, 0, 0, 0};
    if (mu_s) { ms0 = ((const float4*)mu_s)[2 * q]; ms1 = ((const float4*)mu_s)[2 * q + 1]; }
    const int j0 = l & 15;
    float bbv[4];
#pragma unroll
    for (int nt = 0; nt < 4; ++nt)
        bbv[nt] = 0.25f * (bias[nt * 16 + j0] + bias[64 + nt * 16 + j0] +
                           bias[128 + nt * 16 + j0] + bias[192 + nt * 16 + j0]);
    __syncthreads();   // pl ready; only barrier

    if (V != 1) {
        // gather: each group walks its own rows' edge lists
#pragma unroll
        for (int c = 0; c < NCOLS; ++c)
#pragma unroll
            for (int i = 0; i < 2; ++i) {
                int r = w * 16 + i * 8 + g;
                int p0 = pl[c][r], p1 = pl[c][r + 1];
                for (int e = p0; e < p1; ++e) {
                    float4 u0, u1;
                    ldrow<INBF>(h_src, (size_t)col[e], q, u0, u1);
                    t0[c][i].x += u0.x; t0[c][i].y += u0.y;
                    t0[c][i].z += u0.z; t0[c][i].w += u0.w;
                    t1[c][i].x += u1.x; t1[c][i].y += u1.y;
                    t1[c][i].z += u1.z; t1[c][i].w += u1.w;
                }
            }
    }

    float* pw = (float*)aBuf[w];    // 4 KB per-wave staging (16 rows x 64 f32)
    f32x4 macc[4] = {};
    float4 s0[2], s1[2];            // V2 path accumulators
    if (V == 2) {
#pragma unroll
        for (int i = 0; i < 2; ++i) { s0[i] = {0,0,0,0}; s1[i] = {0,0,0,0}; }
    }

#pragma unroll
    for (int c = 0; c < NCOLS; ++c) {
        if (V == 2) {
#pragma unroll
            for (int i = 0; i < 2; ++i) {
                int row = w * 16 + i * 8 + g;
                float dg = (float)(pl[c][row + 1] - pl[c][row]);
                float scv = 1.0f / (dg + 1.0f);
                s0[i].x += (t0[c][i].x - dg * ms0.x) * scv;
                s0[i].y += (t0[c][i].y - dg * ms0.y) * scv;
                s0[i].z += (t0[c][i].z - dg * ms0.z) * scv;
                s0[i].w += (t0[c][i].w - dg * ms0.w) * scv;
                s1[i].x += (t1[c][i].x - dg * ms1.x) * scv;
                s1[i].y += (t1[c][i].y - dg * ms1.y) * scv;
                s1[i].z += (t1[c][i].z - dg * ms1.z) * scv;
                s1[i].w += (t1[c][i].w - dg * ms1.w) * scv;
            }
            continue;
        }
        // scale -> packed bf16 hi/lo -> LDS
#pragma unroll
        for (int i = 0; i < 2; ++i) {
            int rloc = i * 8 + g;
            int row = w * 16 + rloc;
            float dg = (float)(pl[c][row + 1] - pl[c][row]);
            float scv = 1.0f / (dg + 1.0f);
            float4 a = t0[c][i], b = t1[c][i];
            a.x = (a.x - dg * ms0.x) * scv; a.y = (a.y - dg * ms0.y) * scv;
            a.z = (a.z - dg * ms0.z) * scv; a.w = (a.w - dg * ms0.w) * scv;
            b.x = (b.x - dg * ms1.x) * scv; b.y = (b.y - dg * ms1.y) * scv;
            b.z = (b.z - dg * ms1.z) * scv; b.w = (b.w - dg * ms1.w) * scv;
            unsigned int h01 = cvtpk(a.x, a.y), h23 = cvtpk(a.z, a.w);
            unsigned int h45 = cvtpk(b.x, b.y), h67 = cvtpk(b.z, b.w);
            float r0 = a.x - __uint_as_float(h01 << 16);
            float r1 = a.y - __uint_as_float(h01 & 0xFFFF0000u);
            float r2 = a.z - __uint_as_float(h23 << 16);
            float r3 = a.w - __uint_as_float(h23 & 0xFFFF0000u);
            float r4 = b.x - __uint_as_float(h45 << 16);
            float r5 = b.y - __uint_as_float(h45 & 0xFFFF0000u);
            float r6 = b.z - __uint_as_float(h67 << 16);
            float r7 = b.w - __uint_as_float(h67 & 0xFFFF0000u);
            unsigned int l01 = cvtpk(r0, r1), l23 = cvtpk(r2, r3);
            unsigned int l45 = cvtpk(r4, r5), l67 = cvtpk(r6, r7);
            int off = swz(rloc, q * 16);
            *(unsigned long long*)((char*)aBuf[w][0] + off) =
                (unsigned long long)h01 | ((unsigned long long)h23 << 32);
            *(unsigned long long*)((char*)aBuf[w][0] + off + 8) =
                (unsigned long long)h45 | ((unsigned long long)h67 << 32);
            *(unsigned long long*)((char*)aBuf[w][1] + off) =
                (unsigned long long)l01 | ((unsigned long long)l23 << 32);
            *(unsigned long long*)((char*)aBuf[w][1] + off + 8) =
                (unsigned long long)l45 | ((unsigned long long)l67 << 32);
        }
        // issue ALL 8 W loads for this relation (latency covered by ds ops below)
        bf16x8 wf[4][2];
#pragma unroll
        for (int nt = 0; nt < 4; ++nt) {
            const unsigned short* wb = Wt + ((c * D + nt * 16 + (l & 15)) * D + (l >> 4) * 8);
            wf[nt][0] = *(const bf16x8*)(wb);
            wf[nt][1] = *(const bf16x8*)(wb + 32);
        }
        bf16x8 ah[2], al[2];
#pragma unroll
        for (int kh = 0; kh < 2; ++kh) {
            int off = swz(l & 15, kh * 64 + (l >> 4) * 16);
            ah[kh] = *(const bf16x8*)((const char*)aBuf[w][0] + off);
            al[kh] = *(const bf16x8*)((const char*)aBuf[w][1] + off);
        }
#pragma unroll
        for (int nt = 0; nt < 4; ++nt) {
            macc[nt] = __builtin_amdgcn_mfma_f32_16x16x32_bf16(ah[0], wf[nt][0], macc[nt], 0, 0, 0);
            macc[nt] = __builtin_amdgcn_mfma_f32_16x16x32_bf16(ah[1], wf[nt][1], macc[nt], 0, 0, 0);
            macc[nt] = __builtin_amdgcn_mfma_f32_16x16x32_bf16(al[0], wf[nt][0], macc[nt], 0, 0, 0);
            macc[nt] = __builtin_amdgcn_mfma_f32_16x16x32_bf16(al[1], wf[nt][1], macc[nt], 0, 0, 0);
        }
    }

    // epilogue: stage into per-wave LDS, then FULL-LINE coalesced stores
    float cs[4] = {0.f, 0.f, 0.f, 0.f};
    if (V == 2) {
#pragma unroll
        for (int i = 0; i < 2; ++i) {
            int rloc = i * 8 + g;
            *(float4*)&pw[rloc * 64 + q * 8]     = s0[i];
            *(float4*)&pw[rloc * 64 + q * 8 + 4] = s1[i];
        }
        cs[0] = s0[0].x; cs[1] = s0[1].x; cs[2] = s1[0].x; cs[3] = s1[1].x;
    } else {
#pragma unroll
        for (int nt = 0; nt < 4; ++nt)
#pragma unroll
            for (int qq = 0; qq < 4; ++qq) {
                int rl = (l >> 4) * 4 + qq;
                float v = 0.25f * macc[nt][qq] + bbv[nt];
                pw[rl * 64 + nt * 16 + j0] = v;
                if (row0 + w * 16 + rl < n_dst) cs[nt] += v;
            }
    }
    // wave-local LDS RAW: same-wave DS ops complete in program order
    const float4* pv = (const float4*)pw;
    if (OUTBF) {
#pragma unroll
        for (int it = 0; it < 2; ++it) {
            int base = it * 512 + l * 8;
            int rl = base >> 6, c0 = base & 63;
            int grow = row0 + w * 16 + rl;
            float4 a = pv[(base >> 2)], b = pv[(base >> 2) + 1];
            int4 st;
            st.x = (int)cvtpk(a.x, a.y); st.y = (int)cvtpk(a.z, a.w);
            st.z = (int)cvtpk(b.x, b.y); st.w = (int)cvtpk(b.z, b.w);
            if (grow < n_dst)
                *(int4*)((unsigned short*)out + (size_t)grow * D + c0) = st;
        }
    } else {
#pragma unroll
        for (int it = 0; it < 4; ++it) {
            int idx = it * 64 + l;
            int rl = idx >> 4;
            int grow = row0 + w * 16 + rl;
            if (grow < n_dst)
                *(float4*)((float*)out + (size_t)grow * D + (idx & 15) * 4) = pv[idx];
        }
    }
#pragma unroll
    for (int nt = 0; nt < 4; ++nt) {
        float v = cs[nt];
        v += __shfl_xor(v, 16);
        v += __shfl_xor(v, 32);
        if (l < 16) atomicAdd(&csum[(blockIdx.x & 63) * 64 + nt * 16 + l], v);
    }
}

// ----------------- reduce 64 replicas -> mean vectors (both node types)
__global__ void finalize2(const float* __restrict__ repA, float* __restrict__ muA,
                          float invA, const float* __restrict__ repB,
                          float* __restrict__ muB, float invB) {
    int j = threadIdx.x;   // 64 threads
    const float* rep = blockIdx.x ? repB : repA;
    float* mu        = blockIdx.x ? muB : muA;
    float inv        = blockIdx.x ? invB : invA;
    float s = 0.f;
    for (int k = 0; k < 64; ++k) s += rep[k * 64 + j];
    mu[j] = s * inv;
}

// ----------------- combine + center + relu (in place on out)
__global__ void final_combine(float* __restrict__ out, const float* __restrict__ rid,
        const float* __restrict__ mu_c, const float* __restrict__ mu_r) {
    int t = blockIdx.x * 256 + threadIdx.x;
    if (t >= N_CELL * D) return;
    int row = t >> 6, j = t & 63;
    float v = (row < N_RID) ? (rid[(size_t)row * D + j] - mu_r[j])
                            : (out[t] - mu_c[j]);
    out[t] = fmaxf(v, 0.0f);
}

extern "C" void kernel_launch(void* const* d_in, const int* in_sizes, int n_in,
                              void* d_out, int out_size, void* d_ws, size_t ws_size,
                              hipStream_t stream) {
    const float* x_rid  = (const float*)d_in[0];
    const float* x_cell = (const float*)d_in[1];
    const int* src_fwd  = (const int*)d_in[2];
    const int* dst_fwd  = (const int*)d_in[3];
    const int* src_rev  = (const int*)d_in[4];
    const int* dst_rev  = (const int*)d_in[5];
    const float* W1f = (const float*)d_in[6];
    const float* b1f = (const float*)d_in[7];
    const float* W1r = (const float*)d_in[8];
    const float* b1r = (const float*)d_in[9];
    const float* W2f = (const float*)d_in[10];
    const float* b2f = (const float*)d_in[11];
    const float* W2r = (const float*)d_in[12];
    const float* b2r = (const float*)d_in[13];
    float* out = (float*)d_out;

    char* p = (char*)d_ws;
    float* rid2 = (float*)p;                     p += (size_t)N_RID * D * 4;
    unsigned short* cell1 = (unsigned short*)p;  p += (size_t)N_CELL * D * 2;
    unsigned short* rid1  = (unsigned short*)p;  p += (size_t)N_RID * D * 2;
    float* csums = (float*)p;                    p += (size_t)5 * 4096 * 4;
    float* mus   = (float*)p;                    p += 4 * 64 * 4;
    int* ptrF = (int*)p;                         p += (size_t)(NBF + 4) * 4;
    int* colF = (int*)p;                         p += (size_t)TOTE * 4;
    int* ptrR = (int*)p;                         p += (size_t)(NBR + 4) * 4;
    int* colR = (int*)p;                         p += (size_t)TOTE * 4;
    unsigned short* Wt1f = (unsigned short*)p;   p += NCOLS * D * D * 2;
    unsigned short* Wt1r = (unsigned short*)p;   p += NCOLS * D * D * 2;
    unsigned short* Wt2f = (unsigned short*)p;   p += NCOLS * D * D * 2;
    unsigned short* Wt2r = (unsigned short*)p;   p += NCOLS * D * D * 2;
    unsigned short* diagC = (unsigned short*)p;  p += (size_t)N_CELL * D * 2;  // 51.2 MB scratch
    unsigned short* diagR = (unsigned short*)p;  p += (size_t)N_RID * D * 2;   // 12.8 MB scratch
    // build-phase overlays inside rid2 region (dead until layer 2)
    int* cntF  = (int*)rid2;
    int* cntR  = cntF + NBF;
    int* csumF = cntR + NBR;
    int* csumR = csumF + 2048;

    float* cs_c1 = csums;
    float* cs_r1 = csums + 4096;
    float* cs_o  = csums + 8192;
    float* cs_r2 = csums + 12288;
    float* cs_dg = csums + 16384;
    float* mu_c1 = mus;
    float* mu_r1 = mus + 64;
    float* mu_o  = mus + 128;
    float* mu_r2 = mus + 192;

    hipMemsetAsync(cntF, 0, (size_t)(NBF + NBR) * sizeof(int), stream);
    hipMemsetAsync(csums, 0, (size_t)5 * 4096 * sizeof(float), stream);

    prep_w<<<(NCOLS * D * D + 255) / 256, 256, 0, stream>>>(W1f, W1r, W2f, W2r,
                                                            Wt1f, Wt1r, Wt2f, Wt2r);

    const int g2e = (2 * TOTE + 255) / 256;
    hist2<<<g2e, 256, 0, stream>>>(dst_fwd, dst_rev, cntF, cntR);
    scan1_2<<<NCHF + NCHR, 256, 0, stream>>>(cntF, ptrF, csumF, cntR, ptrR, csumR);
    scan2_2<<<2, 256, 0, stream>>>(csumF, csumR);
    scan3_2<<<(NBF + 255) / 256 + (NBR + 255) / 256, 256, 0, stream>>>(ptrF, csumF,
                                                                       ptrR, csumR);
    fill2<<<g2e, 256, 0, stream>>>(dst_fwd, src_fwd, ptrF, cntF, colF,
                                   dst_rev, src_rev, ptrR, cntR, colR);

    const int gC = N_CELL / TILE;                 // 6250
    const int gR = (N_RID + TILE - 1) / TILE;     // 1563

    // ---------------- layer 1 (f32 in, bf16 out) ----------------------------
    sage2<0, false, true><<<gC + gR, 256, 0, stream>>>(
        x_cell, x_rid, ptrF, colF, Wt1f, b1f, nullptr, nullptr, cell1, cs_c1,
        x_rid, x_cell, ptrR, colR, Wt1r, b1r, nullptr, nullptr, rid1, cs_r1, gC);
    finalize2<<<2, 64, 0, stream>>>(cs_c1, mu_c1, 1.0f / N_CELL,
                                    cs_r1, mu_r1, 1.0f / N_RID);

    // ---------------- layer 2 (bf16 in, f32 out) ----------------------------
    sage2<0, true, false><<<gC + gR, 256, 0, stream>>>(
        cell1, rid1, ptrF, colF, Wt2f, b2f, mu_c1, mu_r1, out, cs_o,
        rid1, cell1, ptrR, colR, Wt2r, b2r, mu_r1, mu_c1, rid2, cs_r2, gC);
    finalize2<<<2, 64, 0, stream>>>(cs_o, mu_o, 1.0f / N_CELL,
                                    cs_r2, mu_r2, 1.0f / N_RID);

    final_combine<<<(N_CELL * D) / 256, 256, 0, stream>>>(out, rid2, mu_o, mu_r2);

    // ============ DIAGNOSTIC ABLATIONS (scratch outputs; layer-1 shape) ======
    // V1: gather skipped.  V2: transform (W/cvt/LDS/MFMA) skipped.
    sage2<1, false, true><<<gC + gR, 256, 0, stream>>>(
        x_cell, x_rid, ptrF, colF, Wt1f, b1f, nullptr, nullptr, diagC, cs_dg,
        x_rid, x_cell, ptrR, colR, Wt1r, b1r, nullptr, nullptr, diagR, cs_dg, gC);
    sage2<2, false, true><<<gC + gR, 256, 0, stream>>>(
        x_cell, x_rid, ptrF, colF, Wt1f, b1f, nullptr, nullptr, diagC, cs_dg,
        x_rid, x_cell, ptrR, colR, Wt1r, b1r, nullptr, nullptr, diagR, cs_dg, gC);
}